// Round 16
// baseline (254.797 us; speedup 1.0000x reference)
//
#include <hip/hip_runtime.h>
#include <math.h>

// ProbSparse attention (Informer-style). B=4, L=2048, D=1024, H=16, dk=64, u=7.
// ALL projections hi-only fp16 MFMA (z-indexed single launch). Selection is
// two-level screen-and-refine: query-level (margin candidates from hi rowmax)
// then key-level (margin keys from hi dots), with exact fp32 GEMV recompute of
// the few surviving q rows / K rows. Epilogue: fused prep + sparse rows.
#define Bc 4
#define Lc 2048
#define Dc 1024
#define Hc 16
#define DKc 64
#define Uc 7
#define KPc 8           // key-split parts in attention
#define KPNc (Lc / KPc)
#define RPc 8           // key-split parts in refine_hi
#define RPNc (Lc / RPc)
#define MARGINc 0.02f   // query-screen margin on M scale (~33 sigma)
#define MARGIN2c 0.16f  // key-refine margin on unscaled dot scale (~50 sigma)
#define MAXCc 64
#define KMAXc 16

typedef _Float16 half8 __attribute__((ext_vector_type(8)));
typedef _Float16 half4 __attribute__((ext_vector_type(4)));
typedef float f32x4 __attribute__((ext_vector_type(4)));

#define MFMA16(a, b, c) __builtin_amdgcn_mfma_f32_16x16x32_f16(a, b, c, 0, 0, 0)

#define GLOAD16(gsrc, ldst)                                                    \
  __builtin_amdgcn_global_load_lds(                                            \
      (const __attribute__((address_space(1))) void*)(gsrc),                   \
      (__attribute__((address_space(3))) void*)(ldst), 16, 0, 0)

// Stage a [128 rows][64 fp16] tile (row stride ld elems) into LDS, linear dest,
// XOR-swizzled global source: LDS slot s holds global chunk (s&7)^((s>>3)&7).
__device__ __forceinline__ void stage_tile(const _Float16* __restrict__ g, int ld,
                                           _Float16* lds, int t) {
#pragma unroll
  for (int j = 0; j < 4; ++j) {
    int s = t + j * 256;                 // slot 0..1023
    int r = s >> 3;                      // row 0..127
    int c = (s & 7) ^ (r & 7);           // swizzled source chunk
    GLOAD16(g + (size_t)r * ld + c * 8, lds + (size_t)s * 8);
  }
}

// Read an 8-fp16 MFMA fragment from a swizzled [*][64] tile.
__device__ __forceinline__ half8 read_frag(const _Float16* lds, int row, int g) {
  int chunk = g ^ (row & 7);
  return *(const half8*)(lds + (size_t)row * 64 + chunk * 8);
}

// ---------------- fused prep: bias-fill / wo-transpose / x-split / w-splits ----------------
// Segmented grid:
//   [0,2048)        : out <- broadcast bo (grid-stride float4)
//   [2048,3072)     : woT[d][n] = wo[n][d] (32x32 LDS tiles)
//   [3072,11264)    : x -> x1 (hi fp16)
//   [11264,14336)   : wq->wq1, wk->wk1, wv->wv1 (hi fp16)
__global__ __launch_bounds__(256) void prep_kernel(
    const float* __restrict__ bo, float* __restrict__ out,
    const float* __restrict__ wo, float* __restrict__ woT,
    const float* __restrict__ x, _Float16* __restrict__ x1,
    const float* __restrict__ wq, const float* __restrict__ wk,
    const float* __restrict__ wv, _Float16* __restrict__ wq1,
    _Float16* __restrict__ wk1, _Float16* __restrict__ wv1) {
  __shared__ float tile[32][33];
  const int blk = blockIdx.x;
  const int t = threadIdx.x;
  if (blk < 2048) {
    const int total4 = Bc * Lc * Dc / 4;
    int i0 = blk * 256 + t;
    const float4 bv = *(const float4*)(bo + ((i0 & 255) << 2));
    for (int i = i0; i < total4; i += 2048 * 256)
      *(float4*)(out + (size_t)i * 4) = bv;
  } else if (blk < 3072) {
    const int tt = blk - 2048;
    const int bx = (tt & 31) * 32, by = (tt >> 5) * 32;
    const int tx = t & 31, ty = t >> 5;  // 32 x 8
#pragma unroll
    for (int i = 0; i < 32; i += 8)
      tile[ty + i][tx] = wo[(size_t)(by + ty + i) * Dc + bx + tx];
    __syncthreads();
#pragma unroll
    for (int i = 0; i < 32; i += 8)
      woT[(size_t)(bx + ty + i) * Dc + by + tx] = tile[tx][ty + i];
  } else if (blk < 11264) {
    int i = ((blk - 3072) * 256 + t) * 4;
    float4 v = *(const float4*)(x + i);
    half4 o1;
    o1[0] = (_Float16)v.x; o1[1] = (_Float16)v.y;
    o1[2] = (_Float16)v.z; o1[3] = (_Float16)v.w;
    *(half4*)(x1 + i) = o1;
  } else {
    const int WN = Dc * Dc;
    int i = ((blk - 11264) * 256 + t) * 4;
    int m = i / WN;
    int o = i - m * WN;
    const float* src = (m == 0) ? wq : (m == 1) ? wk : wv;
    _Float16* dst = (m == 0) ? wq1 : (m == 1) ? wk1 : wv1;
    float4 v = *(const float4*)(src + o);
    half4 o1;
    o1[0] = (_Float16)v.x; o1[1] = (_Float16)v.y;
    o1[2] = (_Float16)v.z; o1[3] = (_Float16)v.w;
    *(half4*)(dst + o) = o1;
  }
}

// ---------------- hi-only Q/K/V projection GEMM, z-indexed ----------------
// blockIdx.z: 0 -> Q, 1 -> K, 2 -> V. Per-head fp16 output [bh][l][64].
__global__ __launch_bounds__(256, 3) void proj_hiQKV(
    const _Float16* __restrict__ A1, const _Float16* __restrict__ Wq1,
    const _Float16* __restrict__ Wk1, const _Float16* __restrict__ Wv1,
    const float* __restrict__ bq, const float* __restrict__ bk,
    const float* __restrict__ bv, _Float16* __restrict__ dq,
    _Float16* __restrict__ dk, _Float16* __restrict__ dv, int M, int N, int K) {
  const int sel = blockIdx.z;
  const _Float16* W1 = (sel == 0) ? Wq1 : (sel == 1) ? Wk1 : Wv1;
  const float* bias = (sel == 0) ? bq : (sel == 1) ? bk : bv;
  _Float16* d1 = (sel == 0) ? dq : (sel == 1) ? dk : dv;
  __shared__ __align__(16) _Float16 sA1[128 * 64];
  __shared__ __align__(16) _Float16 sW1[128 * 64];
  const int t = threadIdx.x;
  const int l = t & 63;
  const int wid = t >> 6;
  const int wm = wid >> 1, wn = wid & 1;
  const int bm = blockIdx.x * 128;
  const int bn = blockIdx.y * 128;
  f32x4 hi[4][4] = {};
  for (int k0 = 0; k0 < K; k0 += 64) {
    __syncthreads();
    stage_tile(A1 + (size_t)bm * K + k0, K, sA1, t);
    stage_tile(W1 + (size_t)bn * K + k0, K, sW1, t);
    __syncthreads();
#pragma unroll
    for (int ks = 0; ks < 2; ++ks) {
      const int g = ks * 4 + (l >> 4);
      half8 a1[4], b1[4];
#pragma unroll
      for (int i = 0; i < 4; ++i) {
        a1[i] = read_frag(sA1, wm * 64 + i * 16 + (l & 15), g);
        b1[i] = read_frag(sW1, wn * 64 + i * 16 + (l & 15), g);
      }
#pragma unroll
      for (int i = 0; i < 4; ++i)
#pragma unroll
        for (int j = 0; j < 4; ++j)
          hi[i][j] = MFMA16(a1[i], b1[j], hi[i][j]);
    }
  }
#pragma unroll
  for (int i = 0; i < 4; ++i) {
    int m = bm + wm * 64 + i * 16 + ((l >> 4) << 2);
#pragma unroll
    for (int j = 0; j < 4; ++j) {
      int n = bn + wn * 64 + j * 16 + (l & 15);
      float bvv = bias[n];
      int head = n >> 6, d = n & 63;
#pragma unroll
      for (int r = 0; r < 4; ++r) {
        int mm = m + r;
        int bb = mm >> 11, ltok = mm & (Lc - 1);
        size_t o = ((size_t)(bb * Hc + head) * Lc + ltok) * DKc + d;
        d1[o] = (_Float16)(hi[i][j][r] + bvv);
      }
    }
  }
}

// ---------------- hi-only MFMA row-max of QK^T (screening) ----------------
__global__ __launch_bounds__(256, 3) void rowmax_hi(
    const _Float16* __restrict__ Q1, const _Float16* __restrict__ K1,
    float* __restrict__ Mout) {
  __shared__ __align__(16) _Float16 sQ1[128 * 64];
  __shared__ __align__(16) _Float16 sK1[128 * 64];
  __shared__ float Red[2][128];
  const int t = threadIdx.x;
  const int l = t & 63;
  const int wid = t >> 6;
  const int wm = wid >> 1, wn = wid & 1;
  const int bh = blockIdx.x;
  const int q0 = blockIdx.y * 128;
  stage_tile(Q1 + ((size_t)bh * Lc + q0) * DKc, 64, sQ1, t);
  const _Float16* K1b = K1 + (size_t)bh * Lc * DKc;
  float rm[4][4];
#pragma unroll
  for (int i = 0; i < 4; ++i)
#pragma unroll
    for (int r = 0; r < 4; ++r) rm[i][r] = -INFINITY;
  for (int kt = 0; kt < Lc / 128; ++kt) {
    __syncthreads();
    stage_tile(K1b + (size_t)kt * 128 * 64, 64, sK1, t);
    __syncthreads();
    f32x4 hi[4][4] = {};
#pragma unroll
    for (int ks = 0; ks < 2; ++ks) {
      const int g = ks * 4 + (l >> 4);
      half8 a1[4], b1[4];
#pragma unroll
      for (int i = 0; i < 4; ++i) {
        a1[i] = read_frag(sQ1, wm * 64 + i * 16 + (l & 15), g);
        b1[i] = read_frag(sK1, wn * 64 + i * 16 + (l & 15), g);
      }
#pragma unroll
      for (int i = 0; i < 4; ++i)
#pragma unroll
        for (int j = 0; j < 4; ++j)
          hi[i][j] = MFMA16(a1[i], b1[j], hi[i][j]);
    }
#pragma unroll
    for (int i = 0; i < 4; ++i)
#pragma unroll
      for (int j = 0; j < 4; ++j)
#pragma unroll
        for (int r = 0; r < 4; ++r) rm[i][r] = fmaxf(rm[i][r], hi[i][j][r]);
  }
#pragma unroll
  for (int i = 0; i < 4; ++i)
#pragma unroll
    for (int r = 0; r < 4; ++r) {
      float v = rm[i][r];
#pragma unroll
      for (int off = 1; off < 16; off <<= 1) v = fmaxf(v, __shfl_xor(v, off, 64));
      rm[i][r] = v;
    }
  if ((l & 15) == 0) {
#pragma unroll
    for (int i = 0; i < 4; ++i)
#pragma unroll
      for (int r = 0; r < 4; ++r)
        Red[wn][wm * 64 + i * 16 + ((l >> 4) << 2) + r] = rm[i][r];
  }
  __syncthreads();
  if (t < 128)
    Mout[(size_t)bh * Lc + q0 + t] = 0.125f * fmaxf(Red[0][t], Red[1][t]);
}

// ---------------- screening: approx top-7 + margin candidate list ----------------
__global__ __launch_bounds__(256) void screen_kernel(
    const float* __restrict__ Mv, int* __restrict__ cand, int* __restrict__ cnt) {
  __shared__ float s[Lc];
  __shared__ float rv[256];
  __shared__ int ri[256];
  __shared__ float tauS;
  __shared__ int scnt;
  const int t = threadIdx.x;
  const int bh = blockIdx.x;
  const float* Mb = Mv + (size_t)bh * Lc;
  for (int k = t; k < Lc; k += 256) s[k] = Mb[k];
  if (t == 0) scnt = Uc;
  __syncthreads();
  for (int it = 0; it < Uc; ++it) {
    float bv = -INFINITY;
    int bi = 0x7fffffff;
    for (int k = t; k < Lc; k += 256) {
      float v = s[k];
      if (v > bv || (v == bv && k < bi)) { bv = v; bi = k; }
    }
    rv[t] = bv; ri[t] = bi;
    __syncthreads();
    for (int st = 128; st > 0; st >>= 1) {
      if (t < st) {
        float ov = rv[t + st]; int oi = ri[t + st];
        if (ov > rv[t] || (ov == rv[t] && oi < ri[t])) { rv[t] = ov; ri[t] = oi; }
      }
      __syncthreads();
    }
    if (t == 0) {
      cand[bh * MAXCc + it] = ri[0];
      s[ri[0]] = -INFINITY;
      if (it == Uc - 1) tauS = rv[0];
    }
    __syncthreads();
  }
  const float thr = tauS - MARGINc;
  for (int k = t; k < Lc; k += 256) {
    if (s[k] >= thr) {
      int p = atomicAdd(&scnt, 1);
      if (p < MAXCc) cand[bh * MAXCc + p] = k;
    }
  }
  __syncthreads();
  if (t == 0) cnt[bh] = scnt < MAXCc ? scnt : MAXCc;
}

// ---------------- exact q rows for candidates ----------------
// grid (BH=64, MAXC), block 256. bh fastest -> same-head blocks share XCD L2.
__global__ __launch_bounds__(256) void qcand_kernel(
    const float* __restrict__ x, const float* __restrict__ wq,
    const float* __restrict__ bq,
    const int* __restrict__ cand, const int* __restrict__ cnt,
    float* __restrict__ qcand) {
  const int bh = blockIdx.x, slot = blockIdx.y;
  const int b = bh >> 4, h = bh & 15;
  if (slot >= cnt[bh]) return;
  const int lq = cand[bh * MAXCc + slot];
  __shared__ float sx[Dc];
  __shared__ float qs[DKc];
  const int t = threadIdx.x;
  *(float4*)(sx + t * 4) = *(const float4*)(x + ((size_t)b * Lc + lq) * Dc + t * 4);
  __syncthreads();
  const int lane = t & 63, w = t >> 6;
#pragma unroll
  for (int dd = 0; dd < 16; ++dd) {
    const int d = w * 16 + dd;
    const float* wrow = wq + (size_t)(h * DKc + d) * Dc + lane * 16;
    const float* xrow = sx + lane * 16;
    float p = 0.f;
#pragma unroll
    for (int j = 0; j < 16; j += 4) {
      float4 wv = *(const float4*)(wrow + j);
      p += wv.x * xrow[j] + wv.y * xrow[j + 1] + wv.z * xrow[j + 2] + wv.w * xrow[j + 3];
    }
#pragma unroll
    for (int off = 1; off < 64; off <<= 1) p += __shfl_xor(p, off, 64);
    if (lane == 0) qs[d] = p + bq[h * DKc + d];
  }
  __syncthreads();
  if (t < DKc) qcand[((size_t)bh * MAXCc + slot) * DKc + t] = qs[t];
}

// ---------------- refine_hi: hi-dot part maxes per (bh, key-part) ----------------
// grid (BH=64, RP=8), block 256. k1 read once per part; unscaled part maxes.
__global__ __launch_bounds__(256) void refine_hi(
    const _Float16* __restrict__ k1, const float* __restrict__ qcand,
    const int* __restrict__ cnt, float* __restrict__ MhiPart) {
  const int bh = blockIdx.x, p = blockIdx.y;
  const int nc = cnt[bh];
  __shared__ float qs[MAXCc][DKc];   // 16 KB
  __shared__ float red[4][MAXCc];
  const int t = threadIdx.x;
  for (int i = t; i < nc * DKc; i += 256)
    qs[i >> 6][i & 63] = qcand[(size_t)bh * MAXCc * DKc + i];
  __syncthreads();
  const int k = p * RPNc + t;        // RPNc == 256 == blockDim
  const _Float16* K1r = k1 + ((size_t)bh * Lc + k) * DKc;
  float kv[DKc];
#pragma unroll
  for (int c8 = 0; c8 < 8; ++c8) {
    half8 a = *(const half8*)(K1r + c8 * 8);
#pragma unroll
    for (int j = 0; j < 8; ++j) kv[c8 * 8 + j] = (float)a[j];
  }
  const int lane = t & 63, w = t >> 6;
  for (int s = 0; s < nc; ++s) {
    float dot = 0.f;
#pragma unroll
    for (int j = 0; j < DKc; ++j) dot = fmaf(kv[j], qs[s][j], dot);
#pragma unroll
    for (int off = 1; off < 64; off <<= 1) dot = fmaxf(dot, __shfl_xor(dot, off, 64));
    if (lane == 0) red[w][s] = dot;
  }
  __syncthreads();
  if (t < nc)
    MhiPart[((size_t)bh * MAXCc + t) * RPc + p] =
        fmaxf(fmaxf(red[0][t], red[1][t]), fmaxf(red[2][t], red[3][t]));
}

// ---------------- collect_exact: key-level margin + exact fp32 recompute ----------------
// grid (BH=64, MAXC), block 256. Collect keys with hi-dot >= Mhi - MARGIN2,
// recompute those K rows exactly (x@wk GEMV) and the exact max dot.
__global__ __launch_bounds__(256) void collect_exact(
    const float* __restrict__ x, const float* __restrict__ wk,
    const float* __restrict__ bk, const _Float16* __restrict__ k1,
    const float* __restrict__ qcand, const int* __restrict__ cand,
    const int* __restrict__ cnt, const float* __restrict__ MhiPart,
    float* __restrict__ Mex) {
  const int bh = blockIdx.x, slot = blockIdx.y;
  if (slot >= cnt[bh]) return;
  const int b = bh >> 4, h = bh & 15;
  const int t = threadIdx.x;
  const int lane = t & 63, w = t >> 6;
  __shared__ float qs[DKc];
  __shared__ float sxk[Dc];
  __shared__ float kex[DKc];
  __shared__ int keyl[KMAXc];
  __shared__ int nkey;
  __shared__ float thrS;
  __shared__ float emaxS;
  if (t < DKc) qs[t] = qcand[((size_t)bh * MAXCc + slot) * DKc + t];
  if (t == 0) {
    const float* mp = MhiPart + ((size_t)bh * MAXCc + slot) * RPc;
    float m = -INFINITY;
#pragma unroll
    for (int p = 0; p < RPc; ++p) m = fmaxf(m, mp[p]);
    thrS = m - MARGIN2c;
    nkey = 0;
    emaxS = -INFINITY;
  }
  __syncthreads();
  // scan all keys: hi-dot vs this candidate's exact q
  for (int i = 0; i < Lc / 256; ++i) {
    const int k = i * 256 + t;
    const _Float16* K1r = k1 + ((size_t)bh * Lc + k) * DKc;
    float dot = 0.f;
#pragma unroll
    for (int c8 = 0; c8 < 8; ++c8) {
      half8 a = *(const half8*)(K1r + c8 * 8);
#pragma unroll
      for (int j = 0; j < 8; ++j) dot = fmaf((float)a[j], qs[c8 * 8 + j], dot);
    }
    if (dot >= thrS) {
      int p = atomicAdd(&nkey, 1);
      if (p < KMAXc) keyl[p] = k;
    }
  }
  __syncthreads();
  const int nk = nkey < KMAXc ? nkey : KMAXc;
  for (int kk = 0; kk < nk; ++kk) {
    const int key = keyl[kk];
    *(float4*)(sxk + t * 4) = *(const float4*)(x + ((size_t)b * Lc + key) * Dc + t * 4);
    __syncthreads();
    // exact K row: wave w computes d in [w*16, w*16+16), coalesced wk reads
#pragma unroll
    for (int dd = 0; dd < 16; ++dd) {
      const int d = w * 16 + dd;
      const float* wrow = wk + (size_t)(h * DKc + d) * Dc + lane * 16;
      const float* xr = sxk + lane * 16;
      float p = 0.f;
#pragma unroll
      for (int j = 0; j < 16; j += 4) {
        float4 wv = *(const float4*)(wrow + j);
        p += wv.x * xr[j] + wv.y * xr[j + 1] + wv.z * xr[j + 2] + wv.w * xr[j + 3];
      }
#pragma unroll
      for (int off = 1; off < 64; off <<= 1) p += __shfl_xor(p, off, 64);
      if (lane == 0) kex[d] = p + bk[h * DKc + d];
    }
    __syncthreads();
    if (w == 0) {
      float pd = qs[lane] * kex[lane];
#pragma unroll
      for (int off = 1; off < 64; off <<= 1) pd += __shfl_xor(pd, off, 64);
      if (lane == 0) emaxS = fmaxf(emaxS, pd);
    }
    __syncthreads();
  }
  if (t == 0) Mex[(size_t)bh * MAXCc + slot] = 0.125f * emaxS;
}

// ---------------- arbitration: exact top-7, write idx/qsel ----------------
__global__ __launch_bounds__(64) void arbit_kernel(
    const int* __restrict__ cand, const int* __restrict__ cnt,
    const float* __restrict__ Mex, const float* __restrict__ qcand,
    int* __restrict__ idx, float* __restrict__ qsel) {
  const int bh = blockIdx.x;
  const int t = threadIdx.x;
  __shared__ int spicked[MAXCc];
  const int nc = cnt[bh];
  spicked[t] = 0;
  __syncthreads();
  const float myM = (t < nc) ? Mex[(size_t)bh * MAXCc + t] : -INFINITY;
  for (int it = 0; it < Uc; ++it) {
    float v = (t < nc && !spicked[t]) ? myM : -INFINITY;
    int ci = (t < nc && !spicked[t]) ? cand[bh * MAXCc + t] : 0x7fffffff;
    int slot = t;
#pragma unroll
    for (int off = 1; off < 64; off <<= 1) {
      float ov = __shfl_xor(v, off, 64);
      int oci = __shfl_xor(ci, off, 64);
      int osl = __shfl_xor(slot, off, 64);
      if (ov > v || (ov == v && oci < ci)) { v = ov; ci = oci; slot = osl; }
    }
    if (t == 0) idx[bh * Uc + it] = ci;
    spicked[slot] = 1;
    __syncthreads();
    qsel[((size_t)bh * Uc + it) * DKc + t] = qcand[((size_t)bh * MAXCc + slot) * DKc + t];
    __syncthreads();
  }
}

// ------------- attention partials: all 7 queries x one key-slice -------------
// Scores from hi-only K (value-path precision).
__global__ __launch_bounds__(256) void attn_part(
    const float* __restrict__ qsel,
    const _Float16* __restrict__ k1, const _Float16* __restrict__ v1,
    float* __restrict__ Pm, float* __restrict__ Pl, float* __restrict__ Pctx) {
  __shared__ float qs[Uc][DKc];
  __shared__ float ps[Uc][KPNc];
  __shared__ float red[4][Uc][DKc];
  __shared__ float mred[Uc], lred[Uc];
  const int t = threadIdx.x;
  const int kp = blockIdx.x, h = blockIdx.y, b = blockIdx.z;
  const int bh = b * Hc + h;
  const int k0 = kp * KPNc;
  for (int i = t; i < Uc * DKc; i += 256) {
    int u = i >> 6, dd = i & 63;
    qs[u][dd] = qsel[(size_t)(bh * Uc + u) * DKc + dd];
  }
  __syncthreads();
  const size_t krow = ((size_t)bh * Lc + k0 + t) * DKc;
  float s[Uc] = {};
#pragma unroll
  for (int c = 0; c < 8; ++c) {
    half8 a = *(const half8*)(k1 + krow + c * 8);
    float kv[8];
#pragma unroll
    for (int j = 0; j < 8; ++j) kv[j] = (float)a[j];
#pragma unroll
    for (int u = 0; u < Uc; ++u)
#pragma unroll
      for (int j = 0; j < 8; ++j) s[u] = fmaf(kv[j], qs[u][c * 8 + j], s[u]);
  }
#pragma unroll
  for (int u = 0; u < Uc; ++u) ps[u][t] = s[u] * 0.125f;
  __syncthreads();
  const int w = t >> 6, lane = t & 63;
  for (int u = w; u < Uc; u += 4) {
    float m = -INFINITY;
    for (int k = lane; k < KPNc; k += 64) m = fmaxf(m, ps[u][k]);
#pragma unroll
    for (int off = 1; off < 64; off <<= 1) m = fmaxf(m, __shfl_xor(m, off, 64));
    float lsum = 0.f;
    for (int k = lane; k < KPNc; k += 64) {
      float e = expf(ps[u][k] - m);
      ps[u][k] = e;
      lsum += e;
    }
#pragma unroll
    for (int off = 1; off < 64; off <<= 1) lsum += __shfl_xor(lsum, off, 64);
    if (lane == 0) { mred[u] = m; lred[u] = lsum; }
  }
  __syncthreads();
  const int dd = lane, g = w;
  float acc[Uc] = {};
  const _Float16* Vb = v1 + ((size_t)bh * Lc + k0) * DKc + dd;
  for (int kk = g * (KPNc / 4); kk < (g + 1) * (KPNc / 4); ++kk) {
    float v = (float)Vb[(size_t)kk * DKc];
#pragma unroll
    for (int u = 0; u < Uc; ++u) acc[u] = fmaf(ps[u][kk], v, acc[u]);
  }
#pragma unroll
  for (int u = 0; u < Uc; ++u) red[g][u][dd] = acc[u];
  __syncthreads();
  for (int i = t; i < Uc * DKc; i += 256) {
    int u = i >> 6, d2 = i & 63;
    float v = red[0][u][d2] + red[1][u][d2] + red[2][u][d2] + red[3][u][d2];
    Pctx[((size_t)(bh * Uc + u) * KPc + kp) * DKc + d2] = v;
  }
  if (t < Uc) {
    Pm[(bh * Uc + t) * KPc + kp] = mred[t];
    Pl[(bh * Uc + t) * KPc + kp] = lred[t];
  }
}

// ------------- sparse output rows: one block per (bh,u) selection -------------
// Inline partial-combine from Pm/Pl/Pctx; min-writer (smallest matching head)
// dedups rows selected by multiple heads of the same batch. Deterministic.
__global__ __launch_bounds__(256) void sparse_out(
    const int* __restrict__ idx, const float* __restrict__ Pm,
    const float* __restrict__ Pl, const float* __restrict__ Pctx,
    const float* __restrict__ woT, const float* __restrict__ bo,
    float* __restrict__ out) {
  const int g0 = blockIdx.x;            // bh*Uc + u
  const int bh = g0 / Uc;
  const int b = bh >> 4, h = bh & 15;
  const int l = idx[g0];
  const int t = threadIdx.x;
  __shared__ int muh[Hc];
  __shared__ float crow[DKc];
  __shared__ int hmin;
  if (t < Hc) muh[t] = -1;
  if (t == 0) hmin = Hc;
  __syncthreads();
  if (t < Hc * Uc) {
    int hh = t / Uc, uu = t - hh * Uc;
    if (idx[(b * Hc + hh) * Uc + uu] == l) {
      muh[hh] = uu;                     // unique writer per head (rows distinct)
      atomicMin(&hmin, hh);
    }
  }
  __syncthreads();
  if (hmin != h) return;                // only the smallest matching head writes
  float4 acc = {0.f, 0.f, 0.f, 0.f};
  for (int hh = hmin; hh < Hc; ++hh) {
    const int uu = muh[hh];
    if (uu < 0) continue;
    const int g = (b * Hc + hh) * Uc + uu;
    __syncthreads();
    if (t < DKc) {
      float Mx = -INFINITY;
#pragma unroll
      for (int p = 0; p < KPc; ++p) Mx = fmaxf(Mx, Pm[g * KPc + p]);
      float L = 0.f, a = 0.f;
#pragma unroll
      for (int p = 0; p < KPc; ++p) {
        float wgt = expf(Pm[g * KPc + p] - Mx);
        L += wgt * Pl[g * KPc + p];
        a += Pctx[((size_t)g * KPc + p) * DKc + t] * wgt;
      }
      crow[t] = a / L;
    }
    __syncthreads();
    const float* wbase = woT + (size_t)hh * DKc * Dc + t * 4;
#pragma unroll 8
    for (int d = 0; d < DKc; ++d) {
      const float p = crow[d];
      float4 wv = *(const float4*)(wbase + (size_t)d * Dc);
      acc.x = fmaf(p, wv.x, acc.x);
      acc.y = fmaf(p, wv.y, acc.y);
      acc.z = fmaf(p, wv.z, acc.z);
      acc.w = fmaf(p, wv.w, acc.w);
    }
  }
  const float4 bv = *(const float4*)(bo + t * 4);
  float4 o;
  o.x = acc.x + bv.x; o.y = acc.y + bv.y; o.z = acc.z + bv.z; o.w = acc.w + bv.w;
  *(float4*)(out + ((size_t)b * Lc + l) * Dc + t * 4) = o;
}

extern "C" void kernel_launch(void* const* d_in, const int* in_sizes, int n_in,
                              void* d_out, int out_size, void* d_ws, size_t ws_size,
                              hipStream_t stream) {
  const float* x  = (const float*)d_in[0];
  const float* wq = (const float*)d_in[1];
  const float* bq = (const float*)d_in[2];
  const float* wk = (const float*)d_in[3];
  const float* bk = (const float*)d_in[4];
  const float* wv = (const float*)d_in[5];
  const float* bv = (const float*)d_in[6];
  const float* wo = (const float*)d_in[7];
  const float* bo = (const float*)d_in[8];
  float* out = (float*)d_out;

  char* ws = (char*)d_ws;
  size_t off = 0;
  auto alloc = [&](size_t bytes) -> void* {
    void* p = ws + off;
    off += (bytes + 255) & ~(size_t)255;
    return p;
  };
  const size_t NE = (size_t)Bc * Lc * Dc;           // 8388608
  float* Mv   = (float*)alloc(sizeof(float) * (size_t)Bc * Hc * Lc);
  int*   idx  = (int*)alloc(sizeof(int) * (size_t)Bc * Hc * Uc);
  _Float16* x1 = (_Float16*)alloc(2 * NE);
  _Float16* wq1 = (_Float16*)alloc(2 * (size_t)Dc * Dc);
  _Float16* wk1 = (_Float16*)alloc(2 * (size_t)Dc * Dc);
  _Float16* wv1 = (_Float16*)alloc(2 * (size_t)Dc * Dc);
  _Float16* q1h = (_Float16*)alloc(2 * NE);
  _Float16* k1h = (_Float16*)alloc(2 * NE);
  _Float16* v1h = (_Float16*)alloc(2 * NE);
  int*   cand = (int*)alloc(sizeof(int) * (size_t)Bc * Hc * MAXCc);
  int*   cnt  = (int*)alloc(sizeof(int) * (size_t)Bc * Hc);
  float* MhiP = (float*)alloc(sizeof(float) * (size_t)Bc * Hc * MAXCc * RPc);
  float* Mex  = (float*)alloc(sizeof(float) * (size_t)Bc * Hc * MAXCc);
  float* qcand = (float*)alloc(sizeof(float) * (size_t)Bc * Hc * MAXCc * DKc);
  float* qsel = (float*)alloc(sizeof(float) * (size_t)Bc * Hc * Uc * DKc);
  float* Pm   = (float*)alloc(sizeof(float) * (size_t)Bc * Hc * Uc * KPc);
  float* Pl   = (float*)alloc(sizeof(float) * (size_t)Bc * Hc * Uc * KPc);
  float* Pctx = (float*)alloc(sizeof(float) * (size_t)Bc * Hc * Uc * KPc * DKc);
  float* woT  = (float*)alloc(sizeof(float) * (size_t)Dc * Dc);

  const int M = Bc * Lc;                            // 8192
  // fused prep: bias fill + wo transpose + x hi-split + weight hi-splits
  prep_kernel<<<dim3(14336), 256, 0, stream>>>(bo, out, wo, woT, x, x1,
                                               wq, wk, wv, wq1, wk1, wv1);

  // Q + K + V: hi-only fp16 projections, one launch (grid.z selects)
  proj_hiQKV<<<dim3(M / 128, Dc / 128, 3), 256, 0, stream>>>(
      x1, wq1, wk1, wv1, bq, bk, bv, q1h, k1h, v1h, M, Dc, Dc);

  rowmax_hi<<<dim3(Bc * Hc, Lc / 128), 256, 0, stream>>>(q1h, k1h, Mv);

  screen_kernel<<<dim3(Bc * Hc), 256, 0, stream>>>(Mv, cand, cnt);
  qcand_kernel<<<dim3(Bc * Hc, MAXCc), 256, 0, stream>>>(x, wq, bq, cand, cnt, qcand);
  refine_hi<<<dim3(Bc * Hc, RPc), 256, 0, stream>>>(k1h, qcand, cnt, MhiP);
  collect_exact<<<dim3(Bc * Hc, MAXCc), 256, 0, stream>>>(x, wk, bk, k1h, qcand,
                                                          cand, cnt, MhiP, Mex);
  arbit_kernel<<<dim3(Bc * Hc), 64, 0, stream>>>(cand, cnt, Mex, qcand, idx, qsel);
  attn_part<<<dim3(KPc, Hc, Bc), 256, 0, stream>>>(qsel, k1h, v1h, Pm, Pl, Pctx);
  sparse_out<<<dim3(Bc * Hc * Uc), 256, 0, stream>>>(idx, Pm, Pl, Pctx, woT, bo, out);
}

// Round 17
// 250.946 us; speedup vs baseline: 1.0153x; 1.0153x over previous
//
#include <hip/hip_runtime.h>
#include <math.h>

// ProbSparse attention (Informer-style). B=4, L=2048, D=1024, H=16, dk=64, u=7.
// ALL projections hi-only fp16 MFMA (z-indexed single launch). Selection is
// two-level screen-and-refine: query-level (margin candidates from hi rowmax)
// then key-level (margin keys from hi dots, parallel over key-parts), with
// exact fp32 GEMV recompute of surviving q rows / K rows.
#define Bc 4
#define Lc 2048
#define Dc 1024
#define Hc 16
#define DKc 64
#define Uc 7
#define KPc 8           // key-split parts in attention
#define KPNc (Lc / KPc)
#define RPc 8           // key-split parts in refine_hi / collect
#define RPNc (Lc / RPc)
#define MARGINc 0.02f   // query-screen margin on M scale (~33 sigma)
#define MARGIN2c 0.16f  // key-refine margin on unscaled dot scale (~50 sigma)
#define MAXCc 64
#define KMAXc 16

typedef _Float16 half8 __attribute__((ext_vector_type(8)));
typedef _Float16 half4 __attribute__((ext_vector_type(4)));
typedef float f32x4 __attribute__((ext_vector_type(4)));

#define MFMA16(a, b, c) __builtin_amdgcn_mfma_f32_16x16x32_f16(a, b, c, 0, 0, 0)

#define GLOAD16(gsrc, ldst)                                                    \
  __builtin_amdgcn_global_load_lds(                                            \
      (const __attribute__((address_space(1))) void*)(gsrc),                   \
      (__attribute__((address_space(3))) void*)(ldst), 16, 0, 0)

// Stage a [128 rows][64 fp16] tile (row stride ld elems) into LDS, linear dest,
// XOR-swizzled global source: LDS slot s holds global chunk (s&7)^((s>>3)&7).
__device__ __forceinline__ void stage_tile(const _Float16* __restrict__ g, int ld,
                                           _Float16* lds, int t) {
#pragma unroll
  for (int j = 0; j < 4; ++j) {
    int s = t + j * 256;                 // slot 0..1023
    int r = s >> 3;                      // row 0..127
    int c = (s & 7) ^ (r & 7);           // swizzled source chunk
    GLOAD16(g + (size_t)r * ld + c * 8, lds + (size_t)s * 8);
  }
}

// Read an 8-fp16 MFMA fragment from a swizzled [*][64] tile.
__device__ __forceinline__ half8 read_frag(const _Float16* lds, int row, int g) {
  int chunk = g ^ (row & 7);
  return *(const half8*)(lds + (size_t)row * 64 + chunk * 8);
}

// ---------------- fused prep ----------------
// Segmented grid:
//   [0,2048)        : out <- broadcast bo (grid-stride float4)
//   [2048,3072)     : woT[d][n] = wo[n][d] (32x32 LDS tiles)
//   [3072,11264)    : x -> x1 (hi fp16)
//   [11264,14336)   : wq->wq1, wk->wk1, wv->wv1 (hi fp16)
//   [14336,14352)   : zero nkey counters
__global__ __launch_bounds__(256) void prep_kernel(
    const float* __restrict__ bo, float* __restrict__ out,
    const float* __restrict__ wo, float* __restrict__ woT,
    const float* __restrict__ x, _Float16* __restrict__ x1,
    const float* __restrict__ wq, const float* __restrict__ wk,
    const float* __restrict__ wv, _Float16* __restrict__ wq1,
    _Float16* __restrict__ wk1, _Float16* __restrict__ wv1,
    int* __restrict__ nkey) {
  __shared__ float tile[32][33];
  const int blk = blockIdx.x;
  const int t = threadIdx.x;
  if (blk < 2048) {
    const int total4 = Bc * Lc * Dc / 4;
    int i0 = blk * 256 + t;
    const float4 bv = *(const float4*)(bo + ((i0 & 255) << 2));
    for (int i = i0; i < total4; i += 2048 * 256)
      *(float4*)(out + (size_t)i * 4) = bv;
  } else if (blk < 3072) {
    const int tt = blk - 2048;
    const int bx = (tt & 31) * 32, by = (tt >> 5) * 32;
    const int tx = t & 31, ty = t >> 5;  // 32 x 8
#pragma unroll
    for (int i = 0; i < 32; i += 8)
      tile[ty + i][tx] = wo[(size_t)(by + ty + i) * Dc + bx + tx];
    __syncthreads();
#pragma unroll
    for (int i = 0; i < 32; i += 8)
      woT[(size_t)(bx + ty + i) * Dc + by + tx] = tile[tx][ty + i];
  } else if (blk < 11264) {
    int i = ((blk - 3072) * 256 + t) * 4;
    float4 v = *(const float4*)(x + i);
    half4 o1;
    o1[0] = (_Float16)v.x; o1[1] = (_Float16)v.y;
    o1[2] = (_Float16)v.z; o1[3] = (_Float16)v.w;
    *(half4*)(x1 + i) = o1;
  } else if (blk < 14336) {
    const int WN = Dc * Dc;
    int i = ((blk - 11264) * 256 + t) * 4;
    int m = i / WN;
    int o = i - m * WN;
    const float* src = (m == 0) ? wq : (m == 1) ? wk : wv;
    _Float16* dst = (m == 0) ? wq1 : (m == 1) ? wk1 : wv1;
    float4 v = *(const float4*)(src + o);
    half4 o1;
    o1[0] = (_Float16)v.x; o1[1] = (_Float16)v.y;
    o1[2] = (_Float16)v.z; o1[3] = (_Float16)v.w;
    *(half4*)(dst + o) = o1;
  } else {
    int i = (blk - 14336) * 256 + t;
    if (i < Bc * Hc * MAXCc) nkey[i] = 0;
  }
}

// ---------------- hi-only Q/K/V projection GEMM, z-indexed ----------------
__global__ __launch_bounds__(256, 3) void proj_hiQKV(
    const _Float16* __restrict__ A1, const _Float16* __restrict__ Wq1,
    const _Float16* __restrict__ Wk1, const _Float16* __restrict__ Wv1,
    const float* __restrict__ bq, const float* __restrict__ bk,
    const float* __restrict__ bv, _Float16* __restrict__ dq,
    _Float16* __restrict__ dk, _Float16* __restrict__ dv, int M, int N, int K) {
  const int sel = blockIdx.z;
  const _Float16* W1 = (sel == 0) ? Wq1 : (sel == 1) ? Wk1 : Wv1;
  const float* bias = (sel == 0) ? bq : (sel == 1) ? bk : bv;
  _Float16* d1 = (sel == 0) ? dq : (sel == 1) ? dk : dv;
  __shared__ __align__(16) _Float16 sA1[128 * 64];
  __shared__ __align__(16) _Float16 sW1[128 * 64];
  const int t = threadIdx.x;
  const int l = t & 63;
  const int wid = t >> 6;
  const int wm = wid >> 1, wn = wid & 1;
  const int bm = blockIdx.x * 128;
  const int bn = blockIdx.y * 128;
  f32x4 hi[4][4] = {};
  for (int k0 = 0; k0 < K; k0 += 64) {
    __syncthreads();
    stage_tile(A1 + (size_t)bm * K + k0, K, sA1, t);
    stage_tile(W1 + (size_t)bn * K + k0, K, sW1, t);
    __syncthreads();
#pragma unroll
    for (int ks = 0; ks < 2; ++ks) {
      const int g = ks * 4 + (l >> 4);
      half8 a1[4], b1[4];
#pragma unroll
      for (int i = 0; i < 4; ++i) {
        a1[i] = read_frag(sA1, wm * 64 + i * 16 + (l & 15), g);
        b1[i] = read_frag(sW1, wn * 64 + i * 16 + (l & 15), g);
      }
#pragma unroll
      for (int i = 0; i < 4; ++i)
#pragma unroll
        for (int j = 0; j < 4; ++j)
          hi[i][j] = MFMA16(a1[i], b1[j], hi[i][j]);
    }
  }
#pragma unroll
  for (int i = 0; i < 4; ++i) {
    int m = bm + wm * 64 + i * 16 + ((l >> 4) << 2);
#pragma unroll
    for (int j = 0; j < 4; ++j) {
      int n = bn + wn * 64 + j * 16 + (l & 15);
      float bvv = bias[n];
      int head = n >> 6, d = n & 63;
#pragma unroll
      for (int r = 0; r < 4; ++r) {
        int mm = m + r;
        int bb = mm >> 11, ltok = mm & (Lc - 1);
        size_t o = ((size_t)(bb * Hc + head) * Lc + ltok) * DKc + d;
        d1[o] = (_Float16)(hi[i][j][r] + bvv);
      }
    }
  }
}

// ---------------- hi-only MFMA row-max of QK^T (screening) ----------------
__global__ __launch_bounds__(256, 3) void rowmax_hi(
    const _Float16* __restrict__ Q1, const _Float16* __restrict__ K1,
    float* __restrict__ Mout) {
  __shared__ __align__(16) _Float16 sQ1[128 * 64];
  __shared__ __align__(16) _Float16 sK1[128 * 64];
  __shared__ float Red[2][128];
  const int t = threadIdx.x;
  const int l = t & 63;
  const int wid = t >> 6;
  const int wm = wid >> 1, wn = wid & 1;
  const int bh = blockIdx.x;
  const int q0 = blockIdx.y * 128;
  stage_tile(Q1 + ((size_t)bh * Lc + q0) * DKc, 64, sQ1, t);
  const _Float16* K1b = K1 + (size_t)bh * Lc * DKc;
  float rm[4][4];
#pragma unroll
  for (int i = 0; i < 4; ++i)
#pragma unroll
    for (int r = 0; r < 4; ++r) rm[i][r] = -INFINITY;
  for (int kt = 0; kt < Lc / 128; ++kt) {
    __syncthreads();
    stage_tile(K1b + (size_t)kt * 128 * 64, 64, sK1, t);
    __syncthreads();
    f32x4 hi[4][4] = {};
#pragma unroll
    for (int ks = 0; ks < 2; ++ks) {
      const int g = ks * 4 + (l >> 4);
      half8 a1[4], b1[4];
#pragma unroll
      for (int i = 0; i < 4; ++i) {
        a1[i] = read_frag(sQ1, wm * 64 + i * 16 + (l & 15), g);
        b1[i] = read_frag(sK1, wn * 64 + i * 16 + (l & 15), g);
      }
#pragma unroll
      for (int i = 0; i < 4; ++i)
#pragma unroll
        for (int j = 0; j < 4; ++j)
          hi[i][j] = MFMA16(a1[i], b1[j], hi[i][j]);
    }
#pragma unroll
    for (int i = 0; i < 4; ++i)
#pragma unroll
      for (int j = 0; j < 4; ++j)
#pragma unroll
        for (int r = 0; r < 4; ++r) rm[i][r] = fmaxf(rm[i][r], hi[i][j][r]);
  }
#pragma unroll
  for (int i = 0; i < 4; ++i)
#pragma unroll
    for (int r = 0; r < 4; ++r) {
      float v = rm[i][r];
#pragma unroll
      for (int off = 1; off < 16; off <<= 1) v = fmaxf(v, __shfl_xor(v, off, 64));
      rm[i][r] = v;
    }
  if ((l & 15) == 0) {
#pragma unroll
    for (int i = 0; i < 4; ++i)
#pragma unroll
      for (int r = 0; r < 4; ++r)
        Red[wn][wm * 64 + i * 16 + ((l >> 4) << 2) + r] = rm[i][r];
  }
  __syncthreads();
  if (t < 128)
    Mout[(size_t)bh * Lc + q0 + t] = 0.125f * fmaxf(Red[0][t], Red[1][t]);
}

// ---------------- screening: approx top-7 + margin candidate list ----------------
__global__ __launch_bounds__(256) void screen_kernel(
    const float* __restrict__ Mv, int* __restrict__ cand, int* __restrict__ cnt) {
  __shared__ float s[Lc];
  __shared__ float rv[256];
  __shared__ int ri[256];
  __shared__ float tauS;
  __shared__ int scnt;
  const int t = threadIdx.x;
  const int bh = blockIdx.x;
  const float* Mb = Mv + (size_t)bh * Lc;
  for (int k = t; k < Lc; k += 256) s[k] = Mb[k];
  if (t == 0) scnt = Uc;
  __syncthreads();
  for (int it = 0; it < Uc; ++it) {
    float bv = -INFINITY;
    int bi = 0x7fffffff;
    for (int k = t; k < Lc; k += 256) {
      float v = s[k];
      if (v > bv || (v == bv && k < bi)) { bv = v; bi = k; }
    }
    rv[t] = bv; ri[t] = bi;
    __syncthreads();
    for (int st = 128; st > 0; st >>= 1) {
      if (t < st) {
        float ov = rv[t + st]; int oi = ri[t + st];
        if (ov > rv[t] || (ov == rv[t] && oi < ri[t])) { rv[t] = ov; ri[t] = oi; }
      }
      __syncthreads();
    }
    if (t == 0) {
      cand[bh * MAXCc + it] = ri[0];
      s[ri[0]] = -INFINITY;
      if (it == Uc - 1) tauS = rv[0];
    }
    __syncthreads();
  }
  const float thr = tauS - MARGINc;
  for (int k = t; k < Lc; k += 256) {
    if (s[k] >= thr) {
      int p = atomicAdd(&scnt, 1);
      if (p < MAXCc) cand[bh * MAXCc + p] = k;
    }
  }
  __syncthreads();
  if (t == 0) cnt[bh] = scnt < MAXCc ? scnt : MAXCc;
}

// ---------------- exact q rows for candidates ----------------
// grid (BH=64, MAXC), block 256. bh fastest -> same-head blocks share XCD L2.
__global__ __launch_bounds__(256) void qcand_kernel(
    const float* __restrict__ x, const float* __restrict__ wq,
    const float* __restrict__ bq,
    const int* __restrict__ cand, const int* __restrict__ cnt,
    float* __restrict__ qcand) {
  const int bh = blockIdx.x, slot = blockIdx.y;
  const int b = bh >> 4, h = bh & 15;
  if (slot >= cnt[bh]) return;
  const int lq = cand[bh * MAXCc + slot];
  __shared__ float sx[Dc];
  __shared__ float qs[DKc];
  const int t = threadIdx.x;
  *(float4*)(sx + t * 4) = *(const float4*)(x + ((size_t)b * Lc + lq) * Dc + t * 4);
  __syncthreads();
  const int lane = t & 63, w = t >> 6;
#pragma unroll
  for (int dd = 0; dd < 16; ++dd) {
    const int d = w * 16 + dd;
    const float* wrow = wq + (size_t)(h * DKc + d) * Dc + lane * 16;
    const float* xrow = sx + lane * 16;
    float p = 0.f;
#pragma unroll
    for (int j = 0; j < 16; j += 4) {
      float4 wv = *(const float4*)(wrow + j);
      p += wv.x * xrow[j] + wv.y * xrow[j + 1] + wv.z * xrow[j + 2] + wv.w * xrow[j + 3];
    }
#pragma unroll
    for (int off = 1; off < 64; off <<= 1) p += __shfl_xor(p, off, 64);
    if (lane == 0) qs[d] = p + bq[h * DKc + d];
  }
  __syncthreads();
  if (t < DKc) qcand[((size_t)bh * MAXCc + slot) * DKc + t] = qs[t];
}

// ---------------- refine_hi: hi-dot part maxes per (bh, key-part) ----------------
__global__ __launch_bounds__(256) void refine_hi(
    const _Float16* __restrict__ k1, const float* __restrict__ qcand,
    const int* __restrict__ cnt, float* __restrict__ MhiPart) {
  const int bh = blockIdx.x, p = blockIdx.y;
  const int nc = cnt[bh];
  __shared__ float qs[MAXCc][DKc];   // 16 KB
  __shared__ float red[4][MAXCc];
  const int t = threadIdx.x;
  for (int i = t; i < nc * DKc; i += 256)
    qs[i >> 6][i & 63] = qcand[(size_t)bh * MAXCc * DKc + i];
  __syncthreads();
  const int k = p * RPNc + t;        // RPNc == 256 == blockDim
  const _Float16* K1r = k1 + ((size_t)bh * Lc + k) * DKc;
  float kv[DKc];
#pragma unroll
  for (int c8 = 0; c8 < 8; ++c8) {
    half8 a = *(const half8*)(K1r + c8 * 8);
#pragma unroll
    for (int j = 0; j < 8; ++j) kv[c8 * 8 + j] = (float)a[j];
  }
  const int lane = t & 63, w = t >> 6;
  for (int s = 0; s < nc; ++s) {
    float dot = 0.f;
#pragma unroll
    for (int j = 0; j < DKc; ++j) dot = fmaf(kv[j], qs[s][j], dot);
#pragma unroll
    for (int off = 1; off < 64; off <<= 1) dot = fmaxf(dot, __shfl_xor(dot, off, 64));
    if (lane == 0) red[w][s] = dot;
  }
  __syncthreads();
  if (t < nc)
    MhiPart[((size_t)bh * MAXCc + t) * RPc + p] =
        fmaxf(fmaxf(red[0][t], red[1][t]), fmaxf(red[2][t], red[3][t]));
}

// ---------------- collect_part: key-level margin scan, one key per thread ----------------
// grid (BH=64, MAXC, RP=8), block 256. Global threshold from MhiPart maxes;
// qualifying keys appended to keylist via device atomics (set is deterministic).
__global__ __launch_bounds__(256) void collect_part(
    const _Float16* __restrict__ k1, const float* __restrict__ qcand,
    const int* __restrict__ cnt, const float* __restrict__ MhiPart,
    int* __restrict__ keylist, int* __restrict__ nkey) {
  const int bh = blockIdx.x, slot = blockIdx.y, p = blockIdx.z;
  if (slot >= cnt[bh]) return;
  const int t = threadIdx.x;
  __shared__ float qs[DKc];
  __shared__ float thrS;
  if (t < DKc) qs[t] = qcand[((size_t)bh * MAXCc + slot) * DKc + t];
  if (t == 0) {
    const float* mp = MhiPart + ((size_t)bh * MAXCc + slot) * RPc;
    float m = -INFINITY;
#pragma unroll
    for (int q = 0; q < RPc; ++q) m = fmaxf(m, mp[q]);
    thrS = m - MARGIN2c;
  }
  __syncthreads();
  const int k = p * RPNc + t;
  const _Float16* K1r = k1 + ((size_t)bh * Lc + k) * DKc;
  float dot = 0.f;
#pragma unroll
  for (int c8 = 0; c8 < 8; ++c8) {
    half8 a = *(const half8*)(K1r + c8 * 8);
#pragma unroll
    for (int j = 0; j < 8; ++j) dot = fmaf((float)a[j], qs[c8 * 8 + j], dot);
  }
  if (dot >= thrS) {
    int pos = atomicAdd(&nkey[bh * MAXCc + slot], 1);
    if (pos < KMAXc) keylist[((size_t)bh * MAXCc + slot) * KMAXc + pos] = k;
  }
}

// ---------------- exact_keys: exact fp32 recompute of collected keys ----------------
// grid (BH=64, MAXC), block 256. ~1-3 keys per candidate.
__global__ __launch_bounds__(256) void exact_keys(
    const float* __restrict__ x, const float* __restrict__ wk,
    const float* __restrict__ bk, const float* __restrict__ qcand,
    const int* __restrict__ cnt, const int* __restrict__ keylist,
    const int* __restrict__ nkey, float* __restrict__ Mex) {
  const int bh = blockIdx.x, slot = blockIdx.y;
  if (slot >= cnt[bh]) return;
  const int b = bh >> 4, h = bh & 15;
  const int t = threadIdx.x;
  const int lane = t & 63, w = t >> 6;
  __shared__ float qs[DKc];
  __shared__ float sxk[Dc];
  __shared__ float kex[DKc];
  __shared__ float emaxS;
  if (t < DKc) qs[t] = qcand[((size_t)bh * MAXCc + slot) * DKc + t];
  if (t == 0) emaxS = -INFINITY;
  __syncthreads();
  int nk = nkey[bh * MAXCc + slot];
  nk = nk < KMAXc ? nk : KMAXc;
  for (int kk = 0; kk < nk; ++kk) {
    const int key = keylist[((size_t)bh * MAXCc + slot) * KMAXc + kk];
    *(float4*)(sxk + t * 4) = *(const float4*)(x + ((size_t)b * Lc + key) * Dc + t * 4);
    __syncthreads();
#pragma unroll
    for (int dd = 0; dd < 16; ++dd) {
      const int d = w * 16 + dd;
      const float* wrow = wk + (size_t)(h * DKc + d) * Dc + lane * 16;
      const float* xr = sxk + lane * 16;
      float p = 0.f;
#pragma unroll
      for (int j = 0; j < 16; j += 4) {
        float4 wv = *(const float4*)(wrow + j);
        p += wv.x * xr[j] + wv.y * xr[j + 1] + wv.z * xr[j + 2] + wv.w * xr[j + 3];
      }
#pragma unroll
      for (int off = 1; off < 64; off <<= 1) p += __shfl_xor(p, off, 64);
      if (lane == 0) kex[d] = p + bk[h * DKc + d];
    }
    __syncthreads();
    if (w == 0) {
      float pd = qs[lane] * kex[lane];
#pragma unroll
      for (int off = 1; off < 64; off <<= 1) pd += __shfl_xor(pd, off, 64);
      if (lane == 0) emaxS = fmaxf(emaxS, pd);
    }
    __syncthreads();
  }
  if (t == 0) Mex[(size_t)bh * MAXCc + slot] = 0.125f * emaxS;
}

// ---------------- arbitration: exact top-7, write idx/qsel ----------------
__global__ __launch_bounds__(64) void arbit_kernel(
    const int* __restrict__ cand, const int* __restrict__ cnt,
    const float* __restrict__ Mex, const float* __restrict__ qcand,
    int* __restrict__ idx, float* __restrict__ qsel) {
  const int bh = blockIdx.x;
  const int t = threadIdx.x;
  __shared__ int spicked[MAXCc];
  const int nc = cnt[bh];
  spicked[t] = 0;
  __syncthreads();
  const float myM = (t < nc) ? Mex[(size_t)bh * MAXCc + t] : -INFINITY;
  for (int it = 0; it < Uc; ++it) {
    float v = (t < nc && !spicked[t]) ? myM : -INFINITY;
    int ci = (t < nc && !spicked[t]) ? cand[bh * MAXCc + t] : 0x7fffffff;
    int slot = t;
#pragma unroll
    for (int off = 1; off < 64; off <<= 1) {
      float ov = __shfl_xor(v, off, 64);
      int oci = __shfl_xor(ci, off, 64);
      int osl = __shfl_xor(slot, off, 64);
      if (ov > v || (ov == v && oci < ci)) { v = ov; ci = oci; slot = osl; }
    }
    if (t == 0) idx[bh * Uc + it] = ci;
    spicked[slot] = 1;
    __syncthreads();
    qsel[((size_t)bh * Uc + it) * DKc + t] = qcand[((size_t)bh * MAXCc + slot) * DKc + t];
    __syncthreads();
  }
}

// ------------- attention partials: all 7 queries x one key-slice -------------
__global__ __launch_bounds__(256) void attn_part(
    const float* __restrict__ qsel,
    const _Float16* __restrict__ k1, const _Float16* __restrict__ v1,
    float* __restrict__ Pm, float* __restrict__ Pl, float* __restrict__ Pctx) {
  __shared__ float qs[Uc][DKc];
  __shared__ float ps[Uc][KPNc];
  __shared__ float red[4][Uc][DKc];
  __shared__ float mred[Uc], lred[Uc];
  const int t = threadIdx.x;
  const int kp = blockIdx.x, h = blockIdx.y, b = blockIdx.z;
  const int bh = b * Hc + h;
  const int k0 = kp * KPNc;
  for (int i = t; i < Uc * DKc; i += 256) {
    int u = i >> 6, dd = i & 63;
    qs[u][dd] = qsel[(size_t)(bh * Uc + u) * DKc + dd];
  }
  __syncthreads();
  const size_t krow = ((size_t)bh * Lc + k0 + t) * DKc;
  float s[Uc] = {};
#pragma unroll
  for (int c = 0; c < 8; ++c) {
    half8 a = *(const half8*)(k1 + krow + c * 8);
    float kv[8];
#pragma unroll
    for (int j = 0; j < 8; ++j) kv[j] = (float)a[j];
#pragma unroll
    for (int u = 0; u < Uc; ++u)
#pragma unroll
      for (int j = 0; j < 8; ++j) s[u] = fmaf(kv[j], qs[u][c * 8 + j], s[u]);
  }
#pragma unroll
  for (int u = 0; u < Uc; ++u) ps[u][t] = s[u] * 0.125f;
  __syncthreads();
  const int w = t >> 6, lane = t & 63;
  for (int u = w; u < Uc; u += 4) {
    float m = -INFINITY;
    for (int k = lane; k < KPNc; k += 64) m = fmaxf(m, ps[u][k]);
#pragma unroll
    for (int off = 1; off < 64; off <<= 1) m = fmaxf(m, __shfl_xor(m, off, 64));
    float lsum = 0.f;
    for (int k = lane; k < KPNc; k += 64) {
      float e = expf(ps[u][k] - m);
      ps[u][k] = e;
      lsum += e;
    }
#pragma unroll
    for (int off = 1; off < 64; off <<= 1) lsum += __shfl_xor(lsum, off, 64);
    if (lane == 0) { mred[u] = m; lred[u] = lsum; }
  }
  __syncthreads();
  const int dd = lane, g = w;
  float acc[Uc] = {};
  const _Float16* Vb = v1 + ((size_t)bh * Lc + k0) * DKc + dd;
  for (int kk = g * (KPNc / 4); kk < (g + 1) * (KPNc / 4); ++kk) {
    float v = (float)Vb[(size_t)kk * DKc];
#pragma unroll
    for (int u = 0; u < Uc; ++u) acc[u] = fmaf(ps[u][kk], v, acc[u]);
  }
#pragma unroll
  for (int u = 0; u < Uc; ++u) red[g][u][dd] = acc[u];
  __syncthreads();
  for (int i = t; i < Uc * DKc; i += 256) {
    int u = i >> 6, d2 = i & 63;
    float v = red[0][u][d2] + red[1][u][d2] + red[2][u][d2] + red[3][u][d2];
    Pctx[((size_t)(bh * Uc + u) * KPc + kp) * DKc + d2] = v;
  }
  if (t < Uc) {
    Pm[(bh * Uc + t) * KPc + kp] = mred[t];
    Pl[(bh * Uc + t) * KPc + kp] = lred[t];
  }
}

// ------------- sparse output rows: one block per (bh,u) selection -------------
__global__ __launch_bounds__(256) void sparse_out(
    const int* __restrict__ idx, const float* __restrict__ Pm,
    const float* __restrict__ Pl, const float* __restrict__ Pctx,
    const float* __restrict__ woT, const float* __restrict__ bo,
    float* __restrict__ out) {
  const int g0 = blockIdx.x;            // bh*Uc + u
  const int bh = g0 / Uc;
  const int b = bh >> 4, h = bh & 15;
  const int l = idx[g0];
  const int t = threadIdx.x;
  __shared__ int muh[Hc];
  __shared__ float crow[DKc];
  __shared__ int hmin;
  if (t < Hc) muh[t] = -1;
  if (t == 0) hmin = Hc;
  __syncthreads();
  if (t < Hc * Uc) {
    int hh = t / Uc, uu = t - hh * Uc;
    if (idx[(b * Hc + hh) * Uc + uu] == l) {
      muh[hh] = uu;                     // unique writer per head (rows distinct)
      atomicMin(&hmin, hh);
    }
  }
  __syncthreads();
  if (hmin != h) return;                // only the smallest matching head writes
  float4 acc = {0.f, 0.f, 0.f, 0.f};
  for (int hh = hmin; hh < Hc; ++hh) {
    const int uu = muh[hh];
    if (uu < 0) continue;
    const int g = (b * Hc + hh) * Uc + uu;
    __syncthreads();
    if (t < DKc) {
      float Mx = -INFINITY;
#pragma unroll
      for (int p = 0; p < KPc; ++p) Mx = fmaxf(Mx, Pm[g * KPc + p]);
      float L = 0.f, a = 0.f;
#pragma unroll
      for (int p = 0; p < KPc; ++p) {
        float wgt = expf(Pm[g * KPc + p] - Mx);
        L += wgt * Pl[g * KPc + p];
        a += Pctx[((size_t)g * KPc + p) * DKc + t] * wgt;
      }
      crow[t] = a / L;
    }
    __syncthreads();
    const float* wbase = woT + (size_t)hh * DKc * Dc + t * 4;
#pragma unroll 8
    for (int d = 0; d < DKc; ++d) {
      const float p = crow[d];
      float4 wv = *(const float4*)(wbase + (size_t)d * Dc);
      acc.x = fmaf(p, wv.x, acc.x);
      acc.y = fmaf(p, wv.y, acc.y);
      acc.z = fmaf(p, wv.z, acc.z);
      acc.w = fmaf(p, wv.w, acc.w);
    }
  }
  const float4 bv = *(const float4*)(bo + t * 4);
  float4 o;
  o.x = acc.x + bv.x; o.y = acc.y + bv.y; o.z = acc.z + bv.z; o.w = acc.w + bv.w;
  *(float4*)(out + ((size_t)b * Lc + l) * Dc + t * 4) = o;
}

extern "C" void kernel_launch(void* const* d_in, const int* in_sizes, int n_in,
                              void* d_out, int out_size, void* d_ws, size_t ws_size,
                              hipStream_t stream) {
  const float* x  = (const float*)d_in[0];
  const float* wq = (const float*)d_in[1];
  const float* bq = (const float*)d_in[2];
  const float* wk = (const float*)d_in[3];
  const float* bk = (const float*)d_in[4];
  const float* wv = (const float*)d_in[5];
  const float* bv = (const float*)d_in[6];
  const float* wo = (const float*)d_in[7];
  const float* bo = (const float*)d_in[8];
  float* out = (float*)d_out;

  char* ws = (char*)d_ws;
  size_t off = 0;
  auto alloc = [&](size_t bytes) -> void* {
    void* p = ws + off;
    off += (bytes + 255) & ~(size_t)255;
    return p;
  };
  const size_t NE = (size_t)Bc * Lc * Dc;           // 8388608
  float* Mv   = (float*)alloc(sizeof(float) * (size_t)Bc * Hc * Lc);
  int*   idx  = (int*)alloc(sizeof(int) * (size_t)Bc * Hc * Uc);
  _Float16* x1 = (_Float16*)alloc(2 * NE);
  _Float16* wq1 = (_Float16*)alloc(2 * (size_t)Dc * Dc);
  _Float16* wk1 = (_Float16*)alloc(2 * (size_t)Dc * Dc);
  _Float16* wv1 = (_Float16*)alloc(2 * (size_t)Dc * Dc);
  _Float16* q1h = (_Float16*)alloc(2 * NE);
  _Float16* k1h = (_Float16*)alloc(2 * NE);
  _Float16* v1h = (_Float16*)alloc(2 * NE);
  int*   cand = (int*)alloc(sizeof(int) * (size_t)Bc * Hc * MAXCc);
  int*   cnt  = (int*)alloc(sizeof(int) * (size_t)Bc * Hc);
  float* MhiP = (float*)alloc(sizeof(float) * (size_t)Bc * Hc * MAXCc * RPc);
  float* Mex  = (float*)alloc(sizeof(float) * (size_t)Bc * Hc * MAXCc);
  float* qcand = (float*)alloc(sizeof(float) * (size_t)Bc * Hc * MAXCc * DKc);
  float* qsel = (float*)alloc(sizeof(float) * (size_t)Bc * Hc * Uc * DKc);
  int*   keylist = (int*)alloc(sizeof(int) * (size_t)Bc * Hc * MAXCc * KMAXc);
  int*   nkey    = (int*)alloc(sizeof(int) * (size_t)Bc * Hc * MAXCc);
  float* Pm   = (float*)alloc(sizeof(float) * (size_t)Bc * Hc * Uc * KPc);
  float* Pl   = (float*)alloc(sizeof(float) * (size_t)Bc * Hc * Uc * KPc);
  float* Pctx = (float*)alloc(sizeof(float) * (size_t)Bc * Hc * Uc * KPc * DKc);
  float* woT  = (float*)alloc(sizeof(float) * (size_t)Dc * Dc);

  const int M = Bc * Lc;                            // 8192
  // fused prep: bias fill + wo transpose + hi-splits + nkey zeroing
  prep_kernel<<<dim3(14352), 256, 0, stream>>>(bo, out, wo, woT, x, x1,
                                               wq, wk, wv, wq1, wk1, wv1, nkey);

  // Q + K + V: hi-only fp16 projections, one launch (grid.z selects)
  proj_hiQKV<<<dim3(M / 128, Dc / 128, 3), 256, 0, stream>>>(
      x1, wq1, wk1, wv1, bq, bk, bv, q1h, k1h, v1h, M, Dc, Dc);

  rowmax_hi<<<dim3(Bc * Hc, Lc / 128), 256, 0, stream>>>(q1h, k1h, Mv);

  screen_kernel<<<dim3(Bc * Hc), 256, 0, stream>>>(Mv, cand, cnt);
  qcand_kernel<<<dim3(Bc * Hc, MAXCc), 256, 0, stream>>>(x, wq, bq, cand, cnt, qcand);
  refine_hi<<<dim3(Bc * Hc, RPc), 256, 0, stream>>>(k1h, qcand, cnt, MhiP);
  collect_part<<<dim3(Bc * Hc, MAXCc, RPc), 256, 0, stream>>>(k1h, qcand, cnt,
                                                              MhiP, keylist, nkey);
  exact_keys<<<dim3(Bc * Hc, MAXCc), 256, 0, stream>>>(x, wk, bk, qcand, cnt,
                                                       keylist, nkey, Mex);
  arbit_kernel<<<dim3(Bc * Hc), 64, 0, stream>>>(cand, cnt, Mex, qcand, idx, qsel);
  attn_part<<<dim3(KPc, Hc, Bc), 256, 0, stream>>>(qsel, k1h, v1h, Pm, Pl, Pctx);
  sparse_out<<<dim3(Bc * Hc * Uc), 256, 0, stream>>>(idx, Pm, Pl, Pctx, woT, bo, out);
}

// Round 18
// 240.618 us; speedup vs baseline: 1.0589x; 1.0429x over previous
//
#include <hip/hip_runtime.h>
#include <math.h>

// ProbSparse attention (Informer-style). B=4, L=2048, D=1024, H=16, dk=64, u=7.
// ALL projections hi-only fp16 MFMA (z-indexed single launch). Selection is
// two-level screen-and-refine: query-level (margin candidates from hi rowmax)
// then key-level (margin keys from hi dots, 512 busy blocks), with exact fp32
// GEMV recompute of surviving q rows / K rows.
#define Bc 4
#define Lc 2048
#define Dc 1024
#define Hc 16
#define DKc 64
#define Uc 7
#define KPc 8           // key-split parts in attention
#define KPNc (Lc / KPc)
#define RPc 8           // key-split parts in refine_hi / collect
#define RPNc (Lc / RPc)
#define MARGINc 0.02f   // query-screen margin on M scale (~33 sigma)
#define MARGIN2c 0.16f  // key-refine margin on unscaled dot scale (~50 sigma)
#define MAXCc 64
#define KMAXc 16

typedef _Float16 half8 __attribute__((ext_vector_type(8)));
typedef _Float16 half4 __attribute__((ext_vector_type(4)));
typedef float f32x4 __attribute__((ext_vector_type(4)));

#define MFMA16(a, b, c) __builtin_amdgcn_mfma_f32_16x16x32_f16(a, b, c, 0, 0, 0)

#define GLOAD16(gsrc, ldst)                                                    \
  __builtin_amdgcn_global_load_lds(                                            \
      (const __attribute__((address_space(1))) void*)(gsrc),                   \
      (__attribute__((address_space(3))) void*)(ldst), 16, 0, 0)

// Stage a [128 rows][64 fp16] tile (row stride ld elems) into LDS, linear dest,
// XOR-swizzled global source: LDS slot s holds global chunk (s&7)^((s>>3)&7).
__device__ __forceinline__ void stage_tile(const _Float16* __restrict__ g, int ld,
                                           _Float16* lds, int t) {
#pragma unroll
  for (int j = 0; j < 4; ++j) {
    int s = t + j * 256;                 // slot 0..1023
    int r = s >> 3;                      // row 0..127
    int c = (s & 7) ^ (r & 7);           // swizzled source chunk
    GLOAD16(g + (size_t)r * ld + c * 8, lds + (size_t)s * 8);
  }
}

// Read an 8-fp16 MFMA fragment from a swizzled [*][64] tile.
__device__ __forceinline__ half8 read_frag(const _Float16* lds, int row, int g) {
  int chunk = g ^ (row & 7);
  return *(const half8*)(lds + (size_t)row * 64 + chunk * 8);
}

// ---------------- fused prep ----------------
// Segmented grid:
//   [0,2048)        : out <- broadcast bo (grid-stride float4)
//   [2048,3072)     : woT[d][n] = wo[n][d] (32x32 LDS tiles)
//   [3072,11264)    : x -> x1 (hi fp16)
//   [11264,14336)   : wq->wq1, wk->wk1, wv->wv1 (hi fp16)
//   [14336,14352)   : zero nkey counters
__global__ __launch_bounds__(256) void prep_kernel(
    const float* __restrict__ bo, float* __restrict__ out,
    const float* __restrict__ wo, float* __restrict__ woT,
    const float* __restrict__ x, _Float16* __restrict__ x1,
    const float* __restrict__ wq, const float* __restrict__ wk,
    const float* __restrict__ wv, _Float16* __restrict__ wq1,
    _Float16* __restrict__ wk1, _Float16* __restrict__ wv1,
    int* __restrict__ nkey) {
  __shared__ float tile[32][33];
  const int blk = blockIdx.x;
  const int t = threadIdx.x;
  if (blk < 2048) {
    const int total4 = Bc * Lc * Dc / 4;
    int i0 = blk * 256 + t;
    const float4 bv = *(const float4*)(bo + ((i0 & 255) << 2));
    for (int i = i0; i < total4; i += 2048 * 256)
      *(float4*)(out + (size_t)i * 4) = bv;
  } else if (blk < 3072) {
    const int tt = blk - 2048;
    const int bx = (tt & 31) * 32, by = (tt >> 5) * 32;
    const int tx = t & 31, ty = t >> 5;  // 32 x 8
#pragma unroll
    for (int i = 0; i < 32; i += 8)
      tile[ty + i][tx] = wo[(size_t)(by + ty + i) * Dc + bx + tx];
    __syncthreads();
#pragma unroll
    for (int i = 0; i < 32; i += 8)
      woT[(size_t)(bx + ty + i) * Dc + by + tx] = tile[tx][ty + i];
  } else if (blk < 11264) {
    int i = ((blk - 3072) * 256 + t) * 4;
    float4 v = *(const float4*)(x + i);
    half4 o1;
    o1[0] = (_Float16)v.x; o1[1] = (_Float16)v.y;
    o1[2] = (_Float16)v.z; o1[3] = (_Float16)v.w;
    *(half4*)(x1 + i) = o1;
  } else if (blk < 14336) {
    const int WN = Dc * Dc;
    int i = ((blk - 11264) * 256 + t) * 4;
    int m = i / WN;
    int o = i - m * WN;
    const float* src = (m == 0) ? wq : (m == 1) ? wk : wv;
    _Float16* dst = (m == 0) ? wq1 : (m == 1) ? wk1 : wv1;
    float4 v = *(const float4*)(src + o);
    half4 o1;
    o1[0] = (_Float16)v.x; o1[1] = (_Float16)v.y;
    o1[2] = (_Float16)v.z; o1[3] = (_Float16)v.w;
    *(half4*)(dst + o) = o1;
  } else {
    int i = (blk - 14336) * 256 + t;
    if (i < Bc * Hc * MAXCc) nkey[i] = 0;
  }
}

// ---------------- hi-only Q/K/V projection GEMM, z-indexed ----------------
__global__ __launch_bounds__(256, 3) void proj_hiQKV(
    const _Float16* __restrict__ A1, const _Float16* __restrict__ Wq1,
    const _Float16* __restrict__ Wk1, const _Float16* __restrict__ Wv1,
    const float* __restrict__ bq, const float* __restrict__ bk,
    const float* __restrict__ bv, _Float16* __restrict__ dq,
    _Float16* __restrict__ dk, _Float16* __restrict__ dv, int M, int N, int K) {
  const int sel = blockIdx.z;
  const _Float16* W1 = (sel == 0) ? Wq1 : (sel == 1) ? Wk1 : Wv1;
  const float* bias = (sel == 0) ? bq : (sel == 1) ? bk : bv;
  _Float16* d1 = (sel == 0) ? dq : (sel == 1) ? dk : dv;
  __shared__ __align__(16) _Float16 sA1[128 * 64];
  __shared__ __align__(16) _Float16 sW1[128 * 64];
  const int t = threadIdx.x;
  const int l = t & 63;
  const int wid = t >> 6;
  const int wm = wid >> 1, wn = wid & 1;
  const int bm = blockIdx.x * 128;
  const int bn = blockIdx.y * 128;
  f32x4 hi[4][4] = {};
  for (int k0 = 0; k0 < K; k0 += 64) {
    __syncthreads();
    stage_tile(A1 + (size_t)bm * K + k0, K, sA1, t);
    stage_tile(W1 + (size_t)bn * K + k0, K, sW1, t);
    __syncthreads();
#pragma unroll
    for (int ks = 0; ks < 2; ++ks) {
      const int g = ks * 4 + (l >> 4);
      half8 a1[4], b1[4];
#pragma unroll
      for (int i = 0; i < 4; ++i) {
        a1[i] = read_frag(sA1, wm * 64 + i * 16 + (l & 15), g);
        b1[i] = read_frag(sW1, wn * 64 + i * 16 + (l & 15), g);
      }
#pragma unroll
      for (int i = 0; i < 4; ++i)
#pragma unroll
        for (int j = 0; j < 4; ++j)
          hi[i][j] = MFMA16(a1[i], b1[j], hi[i][j]);
    }
  }
#pragma unroll
  for (int i = 0; i < 4; ++i) {
    int m = bm + wm * 64 + i * 16 + ((l >> 4) << 2);
#pragma unroll
    for (int j = 0; j < 4; ++j) {
      int n = bn + wn * 64 + j * 16 + (l & 15);
      float bvv = bias[n];
      int head = n >> 6, d = n & 63;
#pragma unroll
      for (int r = 0; r < 4; ++r) {
        int mm = m + r;
        int bb = mm >> 11, ltok = mm & (Lc - 1);
        size_t o = ((size_t)(bb * Hc + head) * Lc + ltok) * DKc + d;
        d1[o] = (_Float16)(hi[i][j][r] + bvv);
      }
    }
  }
}

// ---------------- hi-only MFMA row-max of QK^T (screening) ----------------
__global__ __launch_bounds__(256, 3) void rowmax_hi(
    const _Float16* __restrict__ Q1, const _Float16* __restrict__ K1,
    float* __restrict__ Mout) {
  __shared__ __align__(16) _Float16 sQ1[128 * 64];
  __shared__ __align__(16) _Float16 sK1[128 * 64];
  __shared__ float Red[2][128];
  const int t = threadIdx.x;
  const int l = t & 63;
  const int wid = t >> 6;
  const int wm = wid >> 1, wn = wid & 1;
  const int bh = blockIdx.x;
  const int q0 = blockIdx.y * 128;
  stage_tile(Q1 + ((size_t)bh * Lc + q0) * DKc, 64, sQ1, t);
  const _Float16* K1b = K1 + (size_t)bh * Lc * DKc;
  float rm[4][4];
#pragma unroll
  for (int i = 0; i < 4; ++i)
#pragma unroll
    for (int r = 0; r < 4; ++r) rm[i][r] = -INFINITY;
  for (int kt = 0; kt < Lc / 128; ++kt) {
    __syncthreads();
    stage_tile(K1b + (size_t)kt * 128 * 64, 64, sK1, t);
    __syncthreads();
    f32x4 hi[4][4] = {};
#pragma unroll
    for (int ks = 0; ks < 2; ++ks) {
      const int g = ks * 4 + (l >> 4);
      half8 a1[4], b1[4];
#pragma unroll
      for (int i = 0; i < 4; ++i) {
        a1[i] = read_frag(sQ1, wm * 64 + i * 16 + (l & 15), g);
        b1[i] = read_frag(sK1, wn * 64 + i * 16 + (l & 15), g);
      }
#pragma unroll
      for (int i = 0; i < 4; ++i)
#pragma unroll
        for (int j = 0; j < 4; ++j)
          hi[i][j] = MFMA16(a1[i], b1[j], hi[i][j]);
    }
#pragma unroll
    for (int i = 0; i < 4; ++i)
#pragma unroll
      for (int j = 0; j < 4; ++j)
#pragma unroll
        for (int r = 0; r < 4; ++r) rm[i][r] = fmaxf(rm[i][r], hi[i][j][r]);
  }
#pragma unroll
  for (int i = 0; i < 4; ++i)
#pragma unroll
    for (int r = 0; r < 4; ++r) {
      float v = rm[i][r];
#pragma unroll
      for (int off = 1; off < 16; off <<= 1) v = fmaxf(v, __shfl_xor(v, off, 64));
      rm[i][r] = v;
    }
  if ((l & 15) == 0) {
#pragma unroll
    for (int i = 0; i < 4; ++i)
#pragma unroll
      for (int r = 0; r < 4; ++r)
        Red[wn][wm * 64 + i * 16 + ((l >> 4) << 2) + r] = rm[i][r];
  }
  __syncthreads();
  if (t < 128)
    Mout[(size_t)bh * Lc + q0 + t] = 0.125f * fmaxf(Red[0][t], Red[1][t]);
}

// ---------------- screening: approx top-7 + margin candidate list ----------------
__global__ __launch_bounds__(256) void screen_kernel(
    const float* __restrict__ Mv, int* __restrict__ cand, int* __restrict__ cnt) {
  __shared__ float s[Lc];
  __shared__ float rv[256];
  __shared__ int ri[256];
  __shared__ float tauS;
  __shared__ int scnt;
  const int t = threadIdx.x;
  const int bh = blockIdx.x;
  const float* Mb = Mv + (size_t)bh * Lc;
  for (int k = t; k < Lc; k += 256) s[k] = Mb[k];
  if (t == 0) scnt = Uc;
  __syncthreads();
  for (int it = 0; it < Uc; ++it) {
    float bv = -INFINITY;
    int bi = 0x7fffffff;
    for (int k = t; k < Lc; k += 256) {
      float v = s[k];
      if (v > bv || (v == bv && k < bi)) { bv = v; bi = k; }
    }
    rv[t] = bv; ri[t] = bi;
    __syncthreads();
    for (int st = 128; st > 0; st >>= 1) {
      if (t < st) {
        float ov = rv[t + st]; int oi = ri[t + st];
        if (ov > rv[t] || (ov == rv[t] && oi < ri[t])) { rv[t] = ov; ri[t] = oi; }
      }
      __syncthreads();
    }
    if (t == 0) {
      cand[bh * MAXCc + it] = ri[0];
      s[ri[0]] = -INFINITY;
      if (it == Uc - 1) tauS = rv[0];
    }
    __syncthreads();
  }
  const float thr = tauS - MARGINc;
  for (int k = t; k < Lc; k += 256) {
    if (s[k] >= thr) {
      int p = atomicAdd(&scnt, 1);
      if (p < MAXCc) cand[bh * MAXCc + p] = k;
    }
  }
  __syncthreads();
  if (t == 0) cnt[bh] = scnt < MAXCc ? scnt : MAXCc;
}

// ---------------- exact q rows for candidates ----------------
// grid (BH=64, MAXC), block 256. bh fastest -> same-head blocks share XCD L2.
__global__ __launch_bounds__(256) void qcand_kernel(
    const float* __restrict__ x, const float* __restrict__ wq,
    const float* __restrict__ bq,
    const int* __restrict__ cand, const int* __restrict__ cnt,
    float* __restrict__ qcand) {
  const int bh = blockIdx.x, slot = blockIdx.y;
  const int b = bh >> 4, h = bh & 15;
  if (slot >= cnt[bh]) return;
  const int lq = cand[bh * MAXCc + slot];
  __shared__ float sx[Dc];
  __shared__ float qs[DKc];
  const int t = threadIdx.x;
  *(float4*)(sx + t * 4) = *(const float4*)(x + ((size_t)b * Lc + lq) * Dc + t * 4);
  __syncthreads();
  const int lane = t & 63, w = t >> 6;
#pragma unroll
  for (int dd = 0; dd < 16; ++dd) {
    const int d = w * 16 + dd;
    const float* wrow = wq + (size_t)(h * DKc + d) * Dc + lane * 16;
    const float* xrow = sx + lane * 16;
    float p = 0.f;
#pragma unroll
    for (int j = 0; j < 16; j += 4) {
      float4 wv = *(const float4*)(wrow + j);
      p += wv.x * xrow[j] + wv.y * xrow[j + 1] + wv.z * xrow[j + 2] + wv.w * xrow[j + 3];
    }
#pragma unroll
    for (int off = 1; off < 64; off <<= 1) p += __shfl_xor(p, off, 64);
    if (lane == 0) qs[d] = p + bq[h * DKc + d];
  }
  __syncthreads();
  if (t < DKc) qcand[((size_t)bh * MAXCc + slot) * DKc + t] = qs[t];
}

// ---------------- refine_hi: hi-dot part maxes per (bh, key-part) ----------------
__global__ __launch_bounds__(256) void refine_hi(
    const _Float16* __restrict__ k1, const float* __restrict__ qcand,
    const int* __restrict__ cnt, float* __restrict__ MhiPart) {
  const int bh = blockIdx.x, p = blockIdx.y;
  const int nc = cnt[bh];
  __shared__ float qs[MAXCc][DKc];   // 16 KB
  __shared__ float red[4][MAXCc];
  const int t = threadIdx.x;
  for (int i = t; i < nc * DKc; i += 256)
    qs[i >> 6][i & 63] = qcand[(size_t)bh * MAXCc * DKc + i];
  __syncthreads();
  const int k = p * RPNc + t;        // RPNc == 256 == blockDim
  const _Float16* K1r = k1 + ((size_t)bh * Lc + k) * DKc;
  float kv[DKc];
#pragma unroll
  for (int c8 = 0; c8 < 8; ++c8) {
    half8 a = *(const half8*)(K1r + c8 * 8);
#pragma unroll
    for (int j = 0; j < 8; ++j) kv[c8 * 8 + j] = (float)a[j];
  }
  const int lane = t & 63, w = t >> 6;
  for (int s = 0; s < nc; ++s) {
    float dot = 0.f;
#pragma unroll
    for (int j = 0; j < DKc; ++j) dot = fmaf(kv[j], qs[s][j], dot);
#pragma unroll
    for (int off = 1; off < 64; off <<= 1) dot = fmaxf(dot, __shfl_xor(dot, off, 64));
    if (lane == 0) red[w][s] = dot;
  }
  __syncthreads();
  if (t < nc)
    MhiPart[((size_t)bh * MAXCc + t) * RPc + p] =
        fmaxf(fmaxf(red[0][t], red[1][t]), fmaxf(red[2][t], red[3][t]));
}

// ---------------- collect_all: key-level margin scan, 512 busy blocks ----------------
// grid (BH=64, RP=8), block 256. One key per thread (k1 row read once), loops
// candidate slots; margin keys appended via device atomics (set deterministic).
__global__ __launch_bounds__(256) void collect_all(
    const _Float16* __restrict__ k1, const float* __restrict__ qcand,
    const int* __restrict__ cnt, const float* __restrict__ MhiPart,
    int* __restrict__ keylist, int* __restrict__ nkey) {
  const int bh = blockIdx.x, p = blockIdx.y;
  const int nc = cnt[bh];
  __shared__ float qs[MAXCc][DKc];   // 16 KB
  __shared__ float thr[MAXCc];
  const int t = threadIdx.x;
  for (int i = t; i < nc * DKc; i += 256)
    qs[i >> 6][i & 63] = qcand[(size_t)bh * MAXCc * DKc + i];
  if (t < nc) {
    const float* mp = MhiPart + ((size_t)bh * MAXCc + t) * RPc;
    float m = -INFINITY;
#pragma unroll
    for (int q = 0; q < RPc; ++q) m = fmaxf(m, mp[q]);
    thr[t] = m - MARGIN2c;
  }
  __syncthreads();
  const int k = p * RPNc + t;        // RPNc == 256 == blockDim
  const _Float16* K1r = k1 + ((size_t)bh * Lc + k) * DKc;
  float kv[DKc];
#pragma unroll
  for (int c8 = 0; c8 < 8; ++c8) {
    half8 a = *(const half8*)(K1r + c8 * 8);
#pragma unroll
    for (int j = 0; j < 8; ++j) kv[c8 * 8 + j] = (float)a[j];
  }
  for (int s = 0; s < nc; ++s) {
    float dot = 0.f;
#pragma unroll
    for (int j = 0; j < DKc; ++j) dot = fmaf(kv[j], qs[s][j], dot);
    if (dot >= thr[s]) {
      int pos = atomicAdd(&nkey[bh * MAXCc + s], 1);
      if (pos < KMAXc) keylist[((size_t)bh * MAXCc + s) * KMAXc + pos] = k;
    }
  }
}

// ---------------- exact_keys: exact fp32 recompute of collected keys ----------------
// grid (BH=64, MAXC), block 256. ~1-3 keys per candidate.
__global__ __launch_bounds__(256) void exact_keys(
    const float* __restrict__ x, const float* __restrict__ wk,
    const float* __restrict__ bk, const float* __restrict__ qcand,
    const int* __restrict__ cnt, const int* __restrict__ keylist,
    const int* __restrict__ nkey, float* __restrict__ Mex) {
  const int bh = blockIdx.x, slot = blockIdx.y;
  if (slot >= cnt[bh]) return;
  const int b = bh >> 4, h = bh & 15;
  const int t = threadIdx.x;
  const int lane = t & 63, w = t >> 6;
  __shared__ float qs[DKc];
  __shared__ float sxk[Dc];
  __shared__ float kex[DKc];
  __shared__ float emaxS;
  if (t < DKc) qs[t] = qcand[((size_t)bh * MAXCc + slot) * DKc + t];
  if (t == 0) emaxS = -INFINITY;
  __syncthreads();
  int nk = nkey[bh * MAXCc + slot];
  nk = nk < KMAXc ? nk : KMAXc;
  for (int kk = 0; kk < nk; ++kk) {
    const int key = keylist[((size_t)bh * MAXCc + slot) * KMAXc + kk];
    *(float4*)(sxk + t * 4) = *(const float4*)(x + ((size_t)b * Lc + key) * Dc + t * 4);
    __syncthreads();
#pragma unroll
    for (int dd = 0; dd < 16; ++dd) {
      const int d = w * 16 + dd;
      const float* wrow = wk + (size_t)(h * DKc + d) * Dc + lane * 16;
      const float* xr = sxk + lane * 16;
      float p = 0.f;
#pragma unroll
      for (int j = 0; j < 16; j += 4) {
        float4 wv = *(const float4*)(wrow + j);
        p += wv.x * xr[j] + wv.y * xr[j + 1] + wv.z * xr[j + 2] + wv.w * xr[j + 3];
      }
#pragma unroll
      for (int off = 1; off < 64; off <<= 1) p += __shfl_xor(p, off, 64);
      if (lane == 0) kex[d] = p + bk[h * DKc + d];
    }
    __syncthreads();
    if (w == 0) {
      float pd = qs[lane] * kex[lane];
#pragma unroll
      for (int off = 1; off < 64; off <<= 1) pd += __shfl_xor(pd, off, 64);
      if (lane == 0) emaxS = fmaxf(emaxS, pd);
    }
    __syncthreads();
  }
  if (t == 0) Mex[(size_t)bh * MAXCc + slot] = 0.125f * emaxS;
}

// ---------------- arbitration: exact top-7, write idx/qsel ----------------
__global__ __launch_bounds__(64) void arbit_kernel(
    const int* __restrict__ cand, const int* __restrict__ cnt,
    const float* __restrict__ Mex, const float* __restrict__ qcand,
    int* __restrict__ idx, float* __restrict__ qsel) {
  const int bh = blockIdx.x;
  const int t = threadIdx.x;
  __shared__ int spicked[MAXCc];
  const int nc = cnt[bh];
  spicked[t] = 0;
  __syncthreads();
  const float myM = (t < nc) ? Mex[(size_t)bh * MAXCc + t] : -INFINITY;
  for (int it = 0; it < Uc; ++it) {
    float v = (t < nc && !spicked[t]) ? myM : -INFINITY;
    int ci = (t < nc && !spicked[t]) ? cand[bh * MAXCc + t] : 0x7fffffff;
    int slot = t;
#pragma unroll
    for (int off = 1; off < 64; off <<= 1) {
      float ov = __shfl_xor(v, off, 64);
      int oci = __shfl_xor(ci, off, 64);
      int osl = __shfl_xor(slot, off, 64);
      if (ov > v || (ov == v && oci < ci)) { v = ov; ci = oci; slot = osl; }
    }
    if (t == 0) idx[bh * Uc + it] = ci;
    spicked[slot] = 1;
    __syncthreads();
    qsel[((size_t)bh * Uc + it) * DKc + t] = qcand[((size_t)bh * MAXCc + slot) * DKc + t];
    __syncthreads();
  }
}

// ------------- attention partials: all 7 queries x one key-slice -------------
__global__ __launch_bounds__(256) void attn_part(
    const float* __restrict__ qsel,
    const _Float16* __restrict__ k1, const _Float16* __restrict__ v1,
    float* __restrict__ Pm, float* __restrict__ Pl, float* __restrict__ Pctx) {
  __shared__ float qs[Uc][DKc];
  __shared__ float ps[Uc][KPNc];
  __shared__ float red[4][Uc][DKc];
  __shared__ float mred[Uc], lred[Uc];
  const int t = threadIdx.x;
  const int kp = blockIdx.x, h = blockIdx.y, b = blockIdx.z;
  const int bh = b * Hc + h;
  const int k0 = kp * KPNc;
  for (int i = t; i < Uc * DKc; i += 256) {
    int u = i >> 6, dd = i & 63;
    qs[u][dd] = qsel[(size_t)(bh * Uc + u) * DKc + dd];
  }
  __syncthreads();
  const size_t krow = ((size_t)bh * Lc + k0 + t) * DKc;
  float s[Uc] = {};
#pragma unroll
  for (int c = 0; c < 8; ++c) {
    half8 a = *(const half8*)(k1 + krow + c * 8);
    float kv[8];
#pragma unroll
    for (int j = 0; j < 8; ++j) kv[j] = (float)a[j];
#pragma unroll
    for (int u = 0; u < Uc; ++u)
#pragma unroll
      for (int j = 0; j < 8; ++j) s[u] = fmaf(kv[j], qs[u][c * 8 + j], s[u]);
  }
#pragma unroll
  for (int u = 0; u < Uc; ++u) ps[u][t] = s[u] * 0.125f;
  __syncthreads();
  const int w = t >> 6, lane = t & 63;
  for (int u = w; u < Uc; u += 4) {
    float m = -INFINITY;
    for (int k = lane; k < KPNc; k += 64) m = fmaxf(m, ps[u][k]);
#pragma unroll
    for (int off = 1; off < 64; off <<= 1) m = fmaxf(m, __shfl_xor(m, off, 64));
    float lsum = 0.f;
    for (int k = lane; k < KPNc; k += 64) {
      float e = expf(ps[u][k] - m);
      ps[u][k] = e;
      lsum += e;
    }
#pragma unroll
    for (int off = 1; off < 64; off <<= 1) lsum += __shfl_xor(lsum, off, 64);
    if (lane == 0) { mred[u] = m; lred[u] = lsum; }
  }
  __syncthreads();
  const int dd = lane, g = w;
  float acc[Uc] = {};
  const _Float16* Vb = v1 + ((size_t)bh * Lc + k0) * DKc + dd;
  for (int kk = g * (KPNc / 4); kk < (g + 1) * (KPNc / 4); ++kk) {
    float v = (float)Vb[(size_t)kk * DKc];
#pragma unroll
    for (int u = 0; u < Uc; ++u) acc[u] = fmaf(ps[u][kk], v, acc[u]);
  }
#pragma unroll
  for (int u = 0; u < Uc; ++u) red[g][u][dd] = acc[u];
  __syncthreads();
  for (int i = t; i < Uc * DKc; i += 256) {
    int u = i >> 6, d2 = i & 63;
    float v = red[0][u][d2] + red[1][u][d2] + red[2][u][d2] + red[3][u][d2];
    Pctx[((size_t)(bh * Uc + u) * KPc + kp) * DKc + d2] = v;
  }
  if (t < Uc) {
    Pm[(bh * Uc + t) * KPc + kp] = mred[t];
    Pl[(bh * Uc + t) * KPc + kp] = lred[t];
  }
}

// ------------- sparse output rows: one block per (bh,u) selection -------------
__global__ __launch_bounds__(256) void sparse_out(
    const int* __restrict__ idx, const float* __restrict__ Pm,
    const float* __restrict__ Pl, const float* __restrict__ Pctx,
    const float* __restrict__ woT, const float* __restrict__ bo,
    float* __restrict__ out) {
  const int g0 = blockIdx.x;            // bh*Uc + u
  const int bh = g0 / Uc;
  const int b = bh >> 4, h = bh & 15;
  const int l = idx[g0];
  const int t = threadIdx.x;
  __shared__ int muh[Hc];
  __shared__ float crow[DKc];
  __shared__ int hmin;
  if (t < Hc) muh[t] = -1;
  if (t == 0) hmin = Hc;
  __syncthreads();
  if (t < Hc * Uc) {
    int hh = t / Uc, uu = t - hh * Uc;
    if (idx[(b * Hc + hh) * Uc + uu] == l) {
      muh[hh] = uu;                     // unique writer per head (rows distinct)
      atomicMin(&hmin, hh);
    }
  }
  __syncthreads();
  if (hmin != h) return;                // only the smallest matching head writes
  float4 acc = {0.f, 0.f, 0.f, 0.f};
  for (int hh = hmin; hh < Hc; ++hh) {
    const int uu = muh[hh];
    if (uu < 0) continue;
    const int g = (b * Hc + hh) * Uc + uu;
    __syncthreads();
    if (t < DKc) {
      float Mx = -INFINITY;
#pragma unroll
      for (int p = 0; p < KPc; ++p) Mx = fmaxf(Mx, Pm[g * KPc + p]);
      float L = 0.f, a = 0.f;
#pragma unroll
      for (int p = 0; p < KPc; ++p) {
        float wgt = expf(Pm[g * KPc + p] - Mx);
        L += wgt * Pl[g * KPc + p];
        a += Pctx[((size_t)g * KPc + p) * DKc + t] * wgt;
      }
      crow[t] = a / L;
    }
    __syncthreads();
    const float* wbase = woT + (size_t)hh * DKc * Dc + t * 4;
#pragma unroll 8
    for (int d = 0; d < DKc; ++d) {
      const float p = crow[d];
      float4 wv = *(const float4*)(wbase + (size_t)d * Dc);
      acc.x = fmaf(p, wv.x, acc.x);
      acc.y = fmaf(p, wv.y, acc.y);
      acc.z = fmaf(p, wv.z, acc.z);
      acc.w = fmaf(p, wv.w, acc.w);
    }
  }
  const float4 bv = *(const float4*)(bo + t * 4);
  float4 o;
  o.x = acc.x + bv.x; o.y = acc.y + bv.y; o.z = acc.z + bv.z; o.w = acc.w + bv.w;
  *(float4*)(out + ((size_t)b * Lc + l) * Dc + t * 4) = o;
}

extern "C" void kernel_launch(void* const* d_in, const int* in_sizes, int n_in,
                              void* d_out, int out_size, void* d_ws, size_t ws_size,
                              hipStream_t stream) {
  const float* x  = (const float*)d_in[0];
  const float* wq = (const float*)d_in[1];
  const float* bq = (const float*)d_in[2];
  const float* wk = (const float*)d_in[3];
  const float* bk = (const float*)d_in[4];
  const float* wv = (const float*)d_in[5];
  const float* bv = (const float*)d_in[6];
  const float* wo = (const float*)d_in[7];
  const float* bo = (const float*)d_in[8];
  float* out = (float*)d_out;

  char* ws = (char*)d_ws;
  size_t off = 0;
  auto alloc = [&](size_t bytes) -> void* {
    void* p = ws + off;
    off += (bytes + 255) & ~(size_t)255;
    return p;
  };
  const size_t NE = (size_t)Bc * Lc * Dc;           // 8388608
  float* Mv   = (float*)alloc(sizeof(float) * (size_t)Bc * Hc * Lc);
  int*   idx  = (int*)alloc(sizeof(int) * (size_t)Bc * Hc * Uc);
  _Float16* x1 = (_Float16*)alloc(2 * NE);
  _Float16* wq1 = (_Float16*)alloc(2 * (size_t)Dc * Dc);
  _Float16* wk1 = (_Float16*)alloc(2 * (size_t)Dc * Dc);
  _Float16* wv1 = (_Float16*)alloc(2 * (size_t)Dc * Dc);
  _Float16* q1h = (_Float16*)alloc(2 * NE);
  _Float16* k1h = (_Float16*)alloc(2 * NE);
  _Float16* v1h = (_Float16*)alloc(2 * NE);
  int*   cand = (int*)alloc(sizeof(int) * (size_t)Bc * Hc * MAXCc);
  int*   cnt  = (int*)alloc(sizeof(int) * (size_t)Bc * Hc);
  float* MhiP = (float*)alloc(sizeof(float) * (size_t)Bc * Hc * MAXCc * RPc);
  float* Mex  = (float*)alloc(sizeof(float) * (size_t)Bc * Hc * MAXCc);
  float* qcand = (float*)alloc(sizeof(float) * (size_t)Bc * Hc * MAXCc * DKc);
  float* qsel = (float*)alloc(sizeof(float) * (size_t)Bc * Hc * Uc * DKc);
  int*   keylist = (int*)alloc(sizeof(int) * (size_t)Bc * Hc * MAXCc * KMAXc);
  int*   nkey    = (int*)alloc(sizeof(int) * (size_t)Bc * Hc * MAXCc);
  float* Pm   = (float*)alloc(sizeof(float) * (size_t)Bc * Hc * Uc * KPc);
  float* Pl   = (float*)alloc(sizeof(float) * (size_t)Bc * Hc * Uc * KPc);
  float* Pctx = (float*)alloc(sizeof(float) * (size_t)Bc * Hc * Uc * KPc * DKc);
  float* woT  = (float*)alloc(sizeof(float) * (size_t)Dc * Dc);

  const int M = Bc * Lc;                            // 8192
  // fused prep: bias fill + wo transpose + hi-splits + nkey zeroing
  prep_kernel<<<dim3(14352), 256, 0, stream>>>(bo, out, wo, woT, x, x1,
                                               wq, wk, wv, wq1, wk1, wv1, nkey);

  // Q + K + V: hi-only fp16 projections, one launch (grid.z selects)
  proj_hiQKV<<<dim3(M / 128, Dc / 128, 3), 256, 0, stream>>>(
      x1, wq1, wk1, wv1, bq, bk, bv, q1h, k1h, v1h, M, Dc, Dc);

  rowmax_hi<<<dim3(Bc * Hc, Lc / 128), 256, 0, stream>>>(q1h, k1h, Mv);

  screen_kernel<<<dim3(Bc * Hc), 256, 0, stream>>>(Mv, cand, cnt);
  qcand_kernel<<<dim3(Bc * Hc, MAXCc), 256, 0, stream>>>(x, wq, bq, cand, cnt, qcand);
  refine_hi<<<dim3(Bc * Hc, RPc), 256, 0, stream>>>(k1h, qcand, cnt, MhiP);
  collect_all<<<dim3(Bc * Hc, RPc), 256, 0, stream>>>(k1h, qcand, cnt, MhiP,
                                                      keylist, nkey);
  exact_keys<<<dim3(Bc * Hc, MAXCc), 256, 0, stream>>>(x, wk, bk, qcand, cnt,
                                                       keylist, nkey, Mex);
  arbit_kernel<<<dim3(Bc * Hc), 64, 0, stream>>>(cand, cnt, Mex, qcand, idx, qsel);
  attn_part<<<dim3(KPc, Hc, Bc), 256, 0, stream>>>(qsel, k1h, v1h, Pm, Pl, Pctx);
  sparse_out<<<dim3(Bc * Hc * Uc), 256, 0, stream>>>(idx, Pm, Pl, Pctx, woT, bo, out);
}